// Round 1
// baseline (647.458 us; speedup 1.0000x reference)
//
#include <hip/hip_runtime.h>
#include <math.h>

#define S_ROWS 2048
#define T_ROWS 50000
#define DIM    1024
#define KNN    4

#define BM 128
#define BN 128
#define KSL 64                                               /* K-slab bytes (=64 i8) per pipeline stage */
#define NSLAB (DIM / KSL)                                    /* 16 */
#define TILES_PER_CHUNK 4
#define CHUNK_COLS (BN * TILES_PER_CHUNK)                    /* 512   */
#define NUM_CHUNKS ((T_ROWS + CHUNK_COLS - 1) / CHUNK_COLS)  /* 98    */
#define T_PAD (NUM_CHUNKS * CHUNK_COLS)                      /* 50176 */
#define NCAND (NUM_CHUNKS * KNN)                             /* 392   */
#define REFINE 16
#define SP 67  /* sims LDS row stride (ints): odd => conflict-free b32 scan */
#define QSCALE 500.0f

typedef unsigned int uint;
typedef unsigned long long u64;
typedef signed char i8;
typedef __attribute__((ext_vector_type(4))) int i32x4;

// order-preserving pack for signed-i32 sims: key high 32, ~idx low 32
// (lower idx wins exact ties, matching jax.lax.top_k)
__device__ __forceinline__ u64 packI(int v, int idx) {
  return ((u64)((uint)v ^ 0x80000000u) << 32) | (uint)(~idx);
}

template <int N>
__device__ __forceinline__ void insU(u64 p, u64 (&tv)[N]) {
  if (p <= tv[N - 1]) return;
  tv[N - 1] = p;
#pragma unroll
  for (int j = N - 1; j > 0; --j) {
    if (tv[j] > tv[j - 1]) { u64 t = tv[j]; tv[j] = tv[j - 1]; tv[j - 1] = t; }
  }
}

// async global->LDS, 16 B/lane (global_load_lds_dwordx4); dest = wave-uniform
// base + lane*16 (m104/m108) — we pick each lane's global source to implement
// the XOR bank-swizzle.
__device__ __forceinline__ void llds16(const void* g, void* l) {
  __builtin_amdgcn_global_load_lds(
      reinterpret_cast<__attribute__((address_space(1))) void*>(
          reinterpret_cast<uintptr_t>(g)),
      reinterpret_cast<__attribute__((address_space(3))) void*>(
          (unsigned)reinterpret_cast<uintptr_t>(l)),
      16, 0, 0);
}

__device__ __forceinline__ int imax2(int a, int b) { return a > b ? a : b; }

// ---- Kernel 1: normalize rows, quantize to i8 (scale 500), pad with zeros ----
__global__ __launch_bounds__(256) void quant_kernel(const float* __restrict__ in,
                                                    i8* __restrict__ outq, int nvalid) {
  const int row = blockIdx.x;
  const int tid = threadIdx.x;
  if (row >= nvalid) {  // pad rows: zeros => sims 0; scan guards g<T_ROWS anyway
    ((uint*)(outq + ((size_t)row << 10)))[tid] = 0u;
    return;
  }
  __shared__ float red[4];
  float4 v = ((const float4*)(in + ((size_t)row << 10)))[tid];
  float s = v.x * v.x + v.y * v.y + v.z * v.z + v.w * v.w;
#pragma unroll
  for (int off = 32; off; off >>= 1) s += __shfl_down(s, off, 64);
  if ((tid & 63) == 0) red[tid >> 6] = s;
  __syncthreads();
  float tot = red[0] + red[1] + red[2] + red[3];
  float r = QSCALE / fmaxf(sqrtf(tot), 1e-8f);
  int q0 = __float2int_rn(v.x * r), q1 = __float2int_rn(v.y * r);
  int q2 = __float2int_rn(v.z * r), q3 = __float2int_rn(v.w * r);
  q0 = imax2(-127, (q0 < 127 ? q0 : 127));
  q1 = imax2(-127, (q1 < 127 ? q1 : 127));
  q2 = imax2(-127, (q2 < 127 ? q2 : 127));
  q3 = imax2(-127, (q3 < 127 ? q3 : 127));
  uint packed = ((uint)q0 & 255u) | (((uint)q1 & 255u) << 8) |
                (((uint)q2 & 255u) << 16) | (((uint)q3 & 255u) << 24);
  ((uint*)(outq + ((size_t)row << 10)))[tid] = packed;
}

// ---------------- sim kernel: i8 MFMA GEMM + fused per-chunk top-4 ----------
// K-loop is now a depth-1 double-buffered pipeline (T3-minimum, §5 recipe):
// STAGE(next slab -> buf^1) -> ds_read+MFMA(buf) -> __syncthreads.
// The __syncthreads' implicit vmcnt(0) lands AFTER the slab's compute, so
// global->LDS latency overlaps MFMA instead of draining before it.
// K slab halved to 64 B so 2 buffers fit the old 32 KB: union max (sims,
// 34304 B) is unchanged -> occupancy stays 4 blocks/CU.
union __align__(16) SimSmem {
  i8 ab[2][2 * BM * KSL];  // [buf][A 8KB | B 8KB] = 2 x 16 KB
  int sims[BM * SP];       // 34304 B (max member)
  u64 mb[256 * KNN];       // 8 KB merge buffer
};

__device__ __forceinline__ void stage64(const i8* aP, const i8* bP, i8* aL, i8* bL) {
  // per wave: A rows [wave*32, +32), B rows same; 16 rows per llds16 (64 B rows)
  llds16(aP, aL);
  llds16(aP + 16384, aL + 1024);  // +16 global rows
  llds16(bP, bL);
  llds16(bP + 16384, bL + 1024);
}

__device__ __forceinline__ void compute64(const i8* base, int aoff0, int boff0,
                                          i32x4 (&acc)[4][4]) {
  i32x4 af[4], bf[4];
#pragma unroll
  for (int i = 0; i < 4; ++i) af[i] = *(const i32x4*)(base + aoff0 + i * 1024);
#pragma unroll
  for (int j = 0; j < 4; ++j) bf[j] = *(const i32x4*)(base + 8192 + boff0 + j * 1024);
  __builtin_amdgcn_s_setprio(1);
#pragma unroll
  for (int i = 0; i < 4; ++i)
#pragma unroll
    for (int j = 0; j < 4; ++j)
      acc[i][j] = __builtin_amdgcn_mfma_i32_16x16x64_i8(af[i], bf[j], acc[i][j], 0, 0, 0);
  __builtin_amdgcn_s_setprio(0);
}

__global__ __launch_bounds__(256) void sim_i8_kernel(const i8* __restrict__ srcq,
                                                     const i8* __restrict__ tgtq,
                                                     u64* __restrict__ partials) {
  __shared__ SimSmem sm;

  const int tid = threadIdx.x;
  const int lane = tid & 63;
  const int wave = tid >> 6;
  const int qr = (wave >> 1) * 64;  // quadrant row base
  const int qch = wave & 1;         // quadrant col half
  const int m = lane & 15;
  const int quad = lane >> 4;
  const int r0 = blockIdx.x * BM;
  const int chunk = blockIdx.y;

  // staging lane map (64 B LDS rows, 4x 16B blocks): lane i covers local row
  // i>>2, stored block i&3, which must hold logical block (i&3)^(row&3) — the
  // XOR swizzle that keeps frag ds_read_b128 at the 8-access bank-group floor.
  const int srow4 = lane >> 2;
  const int scb4 = (lane & 3) ^ (srow4 & 3);
  const i8* aLane = srcq + (((size_t)(r0 + wave * 32 + srow4)) << 10) + scb4 * 16;

  // frag read offsets: logical k-block q of row r stored at q^(r&3); frag rows
  // have row&3 == m&3, frag k-block == quad (16x16x64 A/B lane layout).
  const int swz = (quad ^ (m & 3)) << 4;
  const int aoff0 = ((qr + m) << 6) + swz;
  const int boff0 = ((qch * 64 + m) << 6) + swz;

  u64 topp[KNN] = {0, 0, 0, 0};
  int thrI = (int)0x80000000;  // INT_MIN

  for (int tile = 0; tile < TILES_PER_CHUNK; ++tile) {
    const int c0 = chunk * CHUNK_COLS + tile * BN;
    const i8* bLane = tgtq + (((size_t)(c0 + wave * 32 + srow4)) << 10) + scb4 * 16;
    i8* aL0 = sm.ab[0] + wave * 2048;
    i8* bL0 = sm.ab[0] + 8192 + wave * 2048;
    i8* aL1 = sm.ab[1] + wave * 2048;
    i8* bL1 = sm.ab[1] + 8192 + wave * 2048;

    i32x4 acc[4][4];
#pragma unroll
    for (int i = 0; i < 4; ++i)
#pragma unroll
      for (int j = 0; j < 4; ++j) acc[i][j] = (i32x4){0, 0, 0, 0};

    // prologue: slab 0 -> buf0 (only full drain in the tile)
    stage64(aLane, bLane, aL0, bL0);
    __syncthreads();

    for (int u = 0; u < NSLAB; u += 2) {
      // even slab u from buf0; stage odd slab u+1 -> buf1 (always valid)
      stage64(aLane + ((u + 1) << 6), bLane + ((u + 1) << 6), aL1, bL1);
      compute64(sm.ab[0], aoff0, boff0, acc);
      __syncthreads();  // vmcnt(0)+barrier AFTER compute: stage latency hidden
      // odd slab u+1 from buf1; stage even slab u+2 -> buf0
      if (u + 2 < NSLAB)
        stage64(aLane + ((u + 2) << 6), bLane + ((u + 2) << 6), aL0, bL0);
      compute64(sm.ab[1], aoff0, boff0, acc);
      __syncthreads();
    }

    // epilogue: C layout row=(lane>>4)*4+reg, col=lane&15 (shape-determined,
    // dtype-independent — m121/m127/m128). Two 64-col phases through LDS.
#pragma unroll
    for (int ph = 0; ph < 2; ++ph) {
      if (qch == ph) {
#pragma unroll
        for (int i = 0; i < 4; ++i)
#pragma unroll
          for (int j = 0; j < 4; ++j)
#pragma unroll
            for (int reg = 0; reg < 4; ++reg)
              sm.sims[(qr + i * 16 + quad * 4 + reg) * SP + j * 16 + m] = acc[i][j][reg];
      }
      __syncthreads();
      {
        const int rowl = tid & 127;
        const int chh = tid >> 7;
        const int* srow = &sm.sims[rowl * SP + chh * 32];
        const int gbase = c0 + ph * 64 + chh * 32;
#pragma unroll
        for (int c = 0; c < 32; c += 4) {
          int a = srow[c], b = srow[c + 1], d2 = srow[c + 2], e = srow[c + 3];
          int mx = imax2(imax2(a, b), imax2(d2, e));
          if (mx > thrI) {  // rare
            const int g = gbase + c;
            if (g + 0 < T_ROWS) insU<KNN>(packI(a, g + 0), topp);
            if (g + 1 < T_ROWS) insU<KNN>(packI(b, g + 1), topp);
            if (g + 2 < T_ROWS) insU<KNN>(packI(d2, g + 2), topp);
            if (g + 3 < T_ROWS) insU<KNN>(packI(e, g + 3), topp);
            thrI = (int)((uint)(topp[KNN - 1] >> 32) ^ 0x80000000u);
          }
        }
      }
      __syncthreads();
    }
  }

  // merge the two col-half owners of each row, write chunk partials
#pragma unroll
  for (int j = 0; j < KNN; ++j) sm.mb[tid * KNN + j] = topp[j];
  __syncthreads();
  if (tid < 128) {
#pragma unroll
    for (int j = 0; j < KNN; ++j) insU<KNN>(sm.mb[(tid + 128) * KNN + j], topp);
    u64* dst = partials + ((size_t)(r0 + tid) * NUM_CHUNKS + chunk) * KNN;
#pragma unroll
    for (int j = 0; j < KNN; ++j) dst[j] = topp[j];
  }
}

// ------- Kernel 3: merge partials -> top-16, fp64 refine, gather+average -----
__global__ __launch_bounds__(256) void merge_gather_kernel(
    const u64* __restrict__ partials, const float* __restrict__ src,
    const float* __restrict__ tgt, float* __restrict__ out) {
  const int row = blockIdx.x;
  const int tid = threadIdx.x;
  const int lane = tid & 63;
  const int wave = tid >> 6;
  __shared__ u64 cbuf[NCAND];
  __shared__ u64 part8[8][REFINE];
  __shared__ int cand[REFINE];
  __shared__ double cval[REFINE];
  __shared__ int fin[KNN];

  for (int c = tid; c < NCAND; c += 256) cbuf[c] = partials[(size_t)row * NCAND + c];
  __syncthreads();

  // stage 1: 8 parallel scanners (one wave, lockstep), top-16 each
  if (tid < 8) {
    u64 t16[REFINE];
#pragma unroll
    for (int j = 0; j < REFINE; ++j) t16[j] = 0;
    const int base = tid * (NCAND / 8);
    for (int c = 0; c < NCAND / 8; ++c) insU<REFINE>(cbuf[base + c], t16);
#pragma unroll
    for (int j = 0; j < REFINE; ++j) part8[tid][j] = t16[j];
  }
  __syncthreads();
  if (tid == 0) {
    u64 t16[REFINE];
#pragma unroll
    for (int j = 0; j < REFINE; ++j) t16[j] = 0;
    for (int s = 0; s < 8; ++s)
#pragma unroll
      for (int j = 0; j < REFINE; ++j) insU<REFINE>(part8[s][j], t16);
#pragma unroll
    for (int j = 0; j < REFINE; ++j) cand[j] = (int)(~(uint)t16[j]);
  }
  __syncthreads();

  // fp64 re-score of the 16 candidates: pins selection to the true fp ordering
  const float4* s4 = (const float4*)(src + ((size_t)row << 10));
  float4 s0 = s4[lane], s1 = s4[lane + 64], s2 = s4[lane + 128], s3 = s4[lane + 192];
  double ss = (double)s0.x * s0.x + (double)s0.y * s0.y + (double)s0.z * s0.z + (double)s0.w * s0.w
            + (double)s1.x * s1.x + (double)s1.y * s1.y + (double)s1.z * s1.z + (double)s1.w * s1.w
            + (double)s2.x * s2.x + (double)s2.y * s2.y + (double)s2.z * s2.z + (double)s2.w * s2.w
            + (double)s3.x * s3.x + (double)s3.y * s3.y + (double)s3.z * s3.z + (double)s3.w * s3.w;
#pragma unroll
  for (int off = 32; off; off >>= 1) ss += __shfl_down(ss, off, 64);
  ss = __shfl(ss, 0, 64);
  const double sn = fmax(sqrt(ss), 1e-8);

  for (int cc = wave; cc < REFINE; cc += 4) {
    const float4* t4 = (const float4*)(tgt + ((size_t)cand[cc] << 10));
    float4 t0 = t4[lane], t1 = t4[lane + 64], t2 = t4[lane + 128], t3 = t4[lane + 192];
    double dd = (double)s0.x * t0.x + (double)s0.y * t0.y + (double)s0.z * t0.z + (double)s0.w * t0.w
              + (double)s1.x * t1.x + (double)s1.y * t1.y + (double)s1.z * t1.z + (double)s1.w * t1.w
              + (double)s2.x * t2.x + (double)s2.y * t2.y + (double)s2.z * t2.z + (double)s2.w * t2.w
              + (double)s3.x * t3.x + (double)s3.y * t3.y + (double)s3.z * t3.z + (double)s3.w * t3.w;
    double tt = (double)t0.x * t0.x + (double)t0.y * t0.y + (double)t0.z * t0.z + (double)t0.w * t0.w
              + (double)t1.x * t1.x + (double)t1.y * t1.y + (double)t1.z * t1.z + (double)t1.w * t1.w
              + (double)t2.x * t2.x + (double)t2.y * t2.y + (double)t2.z * t2.z + (double)t2.w * t2.w
              + (double)t3.x * t3.x + (double)t3.y * t3.y + (double)t3.z * t3.z + (double)t3.w * t3.w;
#pragma unroll
    for (int off = 32; off; off >>= 1) {
      dd += __shfl_down(dd, off, 64);
      tt += __shfl_down(tt, off, 64);
    }
    if (lane == 0) cval[cc] = dd / (sn * fmax(sqrt(tt), 1e-8));
  }
  __syncthreads();

  if (tid == 0) {
    bool used[REFINE];
#pragma unroll
    for (int j = 0; j < REFINE; ++j) used[j] = false;
    for (int k = 0; k < KNN; ++k) {
      int bj = -1; double bv = 0.0; int bidx = 0x7fffffff;
      for (int j = 0; j < REFINE; ++j) {
        if (used[j]) continue;
        if (bj < 0 || cval[j] > bv || (cval[j] == bv && cand[j] < bidx)) {
          bj = j; bv = cval[j]; bidx = cand[j];
        }
      }
      used[bj] = true;
      fin[k] = cand[bj];
    }
  }
  __syncthreads();

  const int d = tid * 4;
  float4 a = *(const float4*)(tgt + ((size_t)fin[0] << 10) + d);
  float4 b = *(const float4*)(tgt + ((size_t)fin[1] << 10) + d);
  float4 c = *(const float4*)(tgt + ((size_t)fin[2] << 10) + d);
  float4 e = *(const float4*)(tgt + ((size_t)fin[3] << 10) + d);
  float4 o;
  o.x = 0.25f * (a.x + b.x + c.x + e.x);
  o.y = 0.25f * (a.y + b.y + c.y + e.y);
  o.z = 0.25f * (a.z + b.z + c.z + e.z);
  o.w = 0.25f * (a.w + b.w + c.w + e.w);
  *(float4*)(out + ((size_t)row << 10) + d) = o;
}

extern "C" void kernel_launch(void* const* d_in, const int* in_sizes, int n_in,
                              void* d_out, int out_size, void* d_ws, size_t ws_size,
                              hipStream_t stream) {
  const float* src = (const float*)d_in[0];
  const float* tgt = (const float*)d_in[1];
  float* out = (float*)d_out;
  char* ws = (char*)d_ws;

  const size_t SRCQ_B = (size_t)S_ROWS << 10;  // 2.10 MB (i8)
  const size_t TGTQ_B = (size_t)T_PAD << 10;   // 51.38 MB (i8)

  i8* srcq = (i8*)ws;
  i8* tgtq = (i8*)(ws + SRCQ_B);
  u64* partials = (u64*)(ws + SRCQ_B + TGTQ_B);  // 6.42 MB; total < 60 MB (ws >= 313 MB proven)

  quant_kernel<<<S_ROWS, 256, 0, stream>>>(src, srcq, S_ROWS);
  quant_kernel<<<T_PAD, 256, 0, stream>>>(tgt, tgtq, T_ROWS);

  dim3 g3(S_ROWS / BM, NUM_CHUNKS);  // x fastest => row-tiles share a tgt chunk in L2
  sim_i8_kernel<<<g3, 256, 0, stream>>>(srcq, tgtq, partials);

  merge_gather_kernel<<<S_ROWS, 256, 0, stream>>>(partials, src, tgt, out);
}

// Round 2
// 631.588 us; speedup vs baseline: 1.0251x; 1.0251x over previous
//
#include <hip/hip_runtime.h>
#include <math.h>

#define S_ROWS 2048
#define T_ROWS 50000
#define DIM    1024
#define KNN    4

#define BM 128
#define BN 128
#define KSL 64                                               /* K-slab bytes (=64 i8) per pipeline stage */
#define NSLAB (DIM / KSL)                                    /* 16 */
#define NBUF 3                                               /* pipeline depth-2 => 3 LDS slab buffers */
#define TILES_PER_CHUNK 4
#define CHUNK_COLS (BN * TILES_PER_CHUNK)                    /* 512   */
#define NUM_CHUNKS ((T_ROWS + CHUNK_COLS - 1) / CHUNK_COLS)  /* 98    */
#define T_PAD (NUM_CHUNKS * CHUNK_COLS)                      /* 50176 */
#define NCAND (NUM_CHUNKS * KNN)                             /* 392   */
#define REFINE 16
#define SP 67  /* sims LDS row stride (ints): odd => conflict-free b32 scan */
#define QSCALE 500.0f

typedef unsigned int uint;
typedef unsigned long long u64;
typedef signed char i8;
typedef __attribute__((ext_vector_type(4))) int i32x4;

// order-preserving pack for signed-i32 sims: key high 32, ~idx low 32
// (lower idx wins exact ties, matching jax.lax.top_k)
__device__ __forceinline__ u64 packI(int v, int idx) {
  return ((u64)((uint)v ^ 0x80000000u) << 32) | (uint)(~idx);
}

template <int N>
__device__ __forceinline__ void insU(u64 p, u64 (&tv)[N]) {
  if (p <= tv[N - 1]) return;
  tv[N - 1] = p;
#pragma unroll
  for (int j = N - 1; j > 0; --j) {
    if (tv[j] > tv[j - 1]) { u64 t = tv[j]; tv[j] = tv[j - 1]; tv[j - 1] = t; }
  }
}

// async global->LDS, 16 B/lane (global_load_lds_dwordx4); dest = wave-uniform
// base + lane*16 (m104/m108) — we pick each lane's global source to implement
// the XOR bank-swizzle.
__device__ __forceinline__ void llds16(const void* g, void* l) {
  __builtin_amdgcn_global_load_lds(
      reinterpret_cast<__attribute__((address_space(1))) void*>(
          reinterpret_cast<uintptr_t>(g)),
      reinterpret_cast<__attribute__((address_space(3))) void*>(
          (unsigned)reinterpret_cast<uintptr_t>(l)),
      16, 0, 0);
}

__device__ __forceinline__ int imax2(int a, int b) { return a > b ? a : b; }

// ---- Kernel 1: normalize rows, quantize to i8 (scale 500), pad with zeros ----
__global__ __launch_bounds__(256) void quant_kernel(const float* __restrict__ in,
                                                    i8* __restrict__ outq, int nvalid) {
  const int row = blockIdx.x;
  const int tid = threadIdx.x;
  if (row >= nvalid) {  // pad rows: zeros => sims 0; scan guards g<T_ROWS anyway
    ((uint*)(outq + ((size_t)row << 10)))[tid] = 0u;
    return;
  }
  __shared__ float red[4];
  float4 v = ((const float4*)(in + ((size_t)row << 10)))[tid];
  float s = v.x * v.x + v.y * v.y + v.z * v.z + v.w * v.w;
#pragma unroll
  for (int off = 32; off; off >>= 1) s += __shfl_down(s, off, 64);
  if ((tid & 63) == 0) red[tid >> 6] = s;
  __syncthreads();
  float tot = red[0] + red[1] + red[2] + red[3];
  float r = QSCALE / fmaxf(sqrtf(tot), 1e-8f);
  int q0 = __float2int_rn(v.x * r), q1 = __float2int_rn(v.y * r);
  int q2 = __float2int_rn(v.z * r), q3 = __float2int_rn(v.w * r);
  q0 = imax2(-127, (q0 < 127 ? q0 : 127));
  q1 = imax2(-127, (q1 < 127 ? q1 : 127));
  q2 = imax2(-127, (q2 < 127 ? q2 : 127));
  q3 = imax2(-127, (q3 < 127 ? q3 : 127));
  uint packed = ((uint)q0 & 255u) | (((uint)q1 & 255u) << 8) |
                (((uint)q2 & 255u) << 16) | (((uint)q3 & 255u) << 24);
  ((uint*)(outq + ((size_t)row << 10)))[tid] = packed;
}

// ---------------- sim kernel: i8 MFMA GEMM + fused per-chunk top-4 ----------
// T3+T4 schedule: depth-2 pipeline over 3 LDS slab buffers, ONE raw s_barrier
// per slab, counted vmcnt(4) (never drained in the loop body).  Per iter k:
//   vmcnt(4)  -> my slab-k DMAs landed (slab-k+1 stays in flight)
//   lgkmcnt(0)-> my iter-(k-1) frag reads done (free: MFMA already waited)
//   s_barrier -> ALL waves: slab-k landed AND reads(k-1) done
//   ds_read frags(k) from buf[k%3]; stage slab k+2 -> buf[(k+2)%3]; MFMA(k)
// WAR safety: buf[(k+2)%3] was last read at iter k-1, proven done pre-barrier.
union __align__(16) SimSmem {
  i8 ab[NBUF][2 * BM * KSL];  // 3 x [A 8KB | B 8KB] = 49152 B (max member)
  int sims[BM * SP];          // 34304 B
  u64 mb[256 * KNN];          // 8 KB merge buffer
};

__device__ __forceinline__ void stage64(const i8* aP, const i8* bP, i8* aL, i8* bL) {
  // per wave: A rows [wave*32, +32), B rows same; 16 rows per llds16 (64 B rows)
  llds16(aP, aL);
  llds16(aP + 16384, aL + 1024);  // +16 global rows
  llds16(bP, bL);
  llds16(bP + 16384, bL + 1024);
}

__global__ __launch_bounds__(256) void sim_i8_kernel(const i8* __restrict__ srcq,
                                                     const i8* __restrict__ tgtq,
                                                     u64* __restrict__ partials) {
  __shared__ SimSmem sm;

  const int tid = threadIdx.x;
  const int lane = tid & 63;
  const int wave = tid >> 6;
  const int qr = (wave >> 1) * 64;  // quadrant row base
  const int qch = wave & 1;         // quadrant col half
  const int m = lane & 15;
  const int quad = lane >> 4;
  const int r0 = blockIdx.x * BM;
  const int chunk = blockIdx.y;

  // staging lane map (64 B LDS rows, 4x 16B blocks): lane i covers local row
  // i>>2, stored block i&3, which must hold logical block (i&3)^(row&3) — the
  // XOR swizzle that keeps frag ds_read_b128 at the 8-access bank-group floor.
  const int srow4 = lane >> 2;
  const int scb4 = (lane & 3) ^ (srow4 & 3);
  const i8* aLane = srcq + (((size_t)(r0 + wave * 32 + srow4)) << 10) + scb4 * 16;

  // frag read offsets: logical k-block q of row r stored at q^(r&3); frag rows
  // have row&3 == m&3, frag k-block == quad (16x16x64 A/B lane layout).
  const int swz = (quad ^ (m & 3)) << 4;
  const int aoff0 = ((qr + m) << 6) + swz;
  const int boff0 = ((qch * 64 + m) << 6) + swz;

  u64 topp[KNN] = {0, 0, 0, 0};
  int thrI = (int)0x80000000;  // INT_MIN

  for (int tile = 0; tile < TILES_PER_CHUNK; ++tile) {
    const int c0 = chunk * CHUNK_COLS + tile * BN;
    const i8* bLane = tgtq + (((size_t)(c0 + wave * 32 + srow4)) << 10) + scb4 * 16;

    i32x4 acc[4][4];
#pragma unroll
    for (int i = 0; i < 4; ++i)
#pragma unroll
      for (int j = 0; j < 4; ++j) acc[i][j] = (i32x4){0, 0, 0, 0};

    // prologue: slabs 0,1 in flight (prior tile's trailing __syncthreads
    // guarantees sims-scan readers are done before these DMA writes land)
    stage64(aLane, bLane, sm.ab[0] + wave * 2048, sm.ab[0] + 8192 + wave * 2048);
    stage64(aLane + 64, bLane + 64, sm.ab[1] + wave * 2048, sm.ab[1] + 8192 + wave * 2048);

#pragma unroll
    for (int k = 0; k < NSLAB; ++k) {
      if (k == NSLAB - 1)
        asm volatile("s_waitcnt vmcnt(0)" ::: "memory");
      else
        asm volatile("s_waitcnt vmcnt(4)" ::: "memory");
      asm volatile("s_waitcnt lgkmcnt(0)" ::: "memory");
      __builtin_amdgcn_s_barrier();
      __builtin_amdgcn_sched_barrier(0);

      const i8* base = sm.ab[k % NBUF];  // k compile-time (full unroll)
      i32x4 af[4], bf[4];
#pragma unroll
      for (int i = 0; i < 4; ++i) af[i] = *(const i32x4*)(base + aoff0 + i * 1024);
#pragma unroll
      for (int j = 0; j < 4; ++j) bf[j] = *(const i32x4*)(base + 8192 + boff0 + j * 1024);

      if (k + 2 < NSLAB) {  // stage slab k+2 two iters ahead
        i8* nb = sm.ab[(k + 2) % NBUF];
        stage64(aLane + ((k + 2) << 6), bLane + ((k + 2) << 6),
                nb + wave * 2048, nb + 8192 + wave * 2048);
      }

      __builtin_amdgcn_s_setprio(1);
#pragma unroll
      for (int i = 0; i < 4; ++i)
#pragma unroll
        for (int j = 0; j < 4; ++j)
          acc[i][j] = __builtin_amdgcn_mfma_i32_16x16x64_i8(af[i], bf[j], acc[i][j], 0, 0, 0);
      __builtin_amdgcn_s_setprio(0);
    }

    // all frag reads proven done (lgkm0+barrier at k=15) but MFMA(15)/epilogue
    // writes of other waves overlap sims (union aliases ab) -> full sync.
    __syncthreads();

    // epilogue: C layout row=(lane>>4)*4+reg, col=lane&15 (shape-determined,
    // dtype-independent — m121/m127/m128). Two 64-col phases through LDS.
#pragma unroll
    for (int ph = 0; ph < 2; ++ph) {
      if (qch == ph) {
#pragma unroll
        for (int i = 0; i < 4; ++i)
#pragma unroll
          for (int j = 0; j < 4; ++j)
#pragma unroll
            for (int reg = 0; reg < 4; ++reg)
              sm.sims[(qr + i * 16 + quad * 4 + reg) * SP + j * 16 + m] = acc[i][j][reg];
      }
      __syncthreads();
      {
        const int rowl = tid & 127;
        const int chh = tid >> 7;
        const int* srow = &sm.sims[rowl * SP + chh * 32];
        const int gbase = c0 + ph * 64 + chh * 32;
#pragma unroll
        for (int c = 0; c < 32; c += 4) {
          int a = srow[c], b = srow[c + 1], d2 = srow[c + 2], e = srow[c + 3];
          int mx = imax2(imax2(a, b), imax2(d2, e));
          if (mx > thrI) {  // rare
            const int g = gbase + c;
            if (g + 0 < T_ROWS) insU<KNN>(packI(a, g + 0), topp);
            if (g + 1 < T_ROWS) insU<KNN>(packI(b, g + 1), topp);
            if (g + 2 < T_ROWS) insU<KNN>(packI(d2, g + 2), topp);
            if (g + 3 < T_ROWS) insU<KNN>(packI(e, g + 3), topp);
            thrI = (int)((uint)(topp[KNN - 1] >> 32) ^ 0x80000000u);
          }
        }
      }
      __syncthreads();
    }
  }

  // merge the two col-half owners of each row, write chunk partials
#pragma unroll
  for (int j = 0; j < KNN; ++j) sm.mb[tid * KNN + j] = topp[j];
  __syncthreads();
  if (tid < 128) {
#pragma unroll
    for (int j = 0; j < KNN; ++j) insU<KNN>(sm.mb[(tid + 128) * KNN + j], topp);
    u64* dst = partials + ((size_t)(r0 + tid) * NUM_CHUNKS + chunk) * KNN;
#pragma unroll
    for (int j = 0; j < KNN; ++j) dst[j] = topp[j];
  }
}

// ------- Kernel 3: merge partials -> top-16, fp64 refine, gather+average -----
__global__ __launch_bounds__(256) void merge_gather_kernel(
    const u64* __restrict__ partials, const float* __restrict__ src,
    const float* __restrict__ tgt, float* __restrict__ out) {
  const int row = blockIdx.x;
  const int tid = threadIdx.x;
  const int lane = tid & 63;
  const int wave = tid >> 6;
  __shared__ u64 cbuf[NCAND];
  __shared__ u64 part8[8][REFINE];
  __shared__ int cand[REFINE];
  __shared__ double cval[REFINE];
  __shared__ int fin[KNN];

  for (int c = tid; c < NCAND; c += 256) cbuf[c] = partials[(size_t)row * NCAND + c];
  __syncthreads();

  // stage 1: 8 parallel scanners (one wave, lockstep), top-16 each
  if (tid < 8) {
    u64 t16[REFINE];
#pragma unroll
    for (int j = 0; j < REFINE; ++j) t16[j] = 0;
    const int base = tid * (NCAND / 8);
    for (int c = 0; c < NCAND / 8; ++c) insU<REFINE>(cbuf[base + c], t16);
#pragma unroll
    for (int j = 0; j < REFINE; ++j) part8[tid][j] = t16[j];
  }
  __syncthreads();
  if (tid == 0) {
    u64 t16[REFINE];
#pragma unroll
    for (int j = 0; j < REFINE; ++j) t16[j] = 0;
    for (int s = 0; s < 8; ++s)
#pragma unroll
      for (int j = 0; j < REFINE; ++j) insU<REFINE>(part8[s][j], t16);
#pragma unroll
    for (int j = 0; j < REFINE; ++j) cand[j] = (int)(~(uint)t16[j]);
  }
  __syncthreads();

  // fp64 re-score of the 16 candidates: pins selection to the true fp ordering
  const float4* s4 = (const float4*)(src + ((size_t)row << 10));
  float4 s0 = s4[lane], s1 = s4[lane + 64], s2 = s4[lane + 128], s3 = s4[lane + 192];
  double ss = (double)s0.x * s0.x + (double)s0.y * s0.y + (double)s0.z * s0.z + (double)s0.w * s0.w
            + (double)s1.x * s1.x + (double)s1.y * s1.y + (double)s1.z * s1.z + (double)s1.w * s1.w
            + (double)s2.x * s2.x + (double)s2.y * s2.y + (double)s2.z * s2.z + (double)s2.w * s2.w
            + (double)s3.x * s3.x + (double)s3.y * s3.y + (double)s3.z * s3.z + (double)s3.w * s3.w;
#pragma unroll
  for (int off = 32; off; off >>= 1) ss += __shfl_down(ss, off, 64);
  ss = __shfl(ss, 0, 64);
  const double sn = fmax(sqrt(ss), 1e-8);

  for (int cc = wave; cc < REFINE; cc += 4) {
    const float4* t4 = (const float4*)(tgt + ((size_t)cand[cc] << 10));
    float4 t0 = t4[lane], t1 = t4[lane + 64], t2 = t4[lane + 128], t3 = t4[lane + 192];
    double dd = (double)s0.x * t0.x + (double)s0.y * t0.y + (double)s0.z * t0.z + (double)s0.w * t0.w
              + (double)s1.x * t1.x + (double)s1.y * t1.y + (double)s1.z * t1.z + (double)s1.w * t1.w
              + (double)s2.x * t2.x + (double)s2.y * t2.y + (double)s2.z * t2.z + (double)s2.w * t2.w
              + (double)s3.x * t3.x + (double)s3.y * t3.y + (double)s3.z * t3.z + (double)s3.w * t3.w;
    double tt = (double)t0.x * t0.x + (double)t0.y * t0.y + (double)t0.z * t0.z + (double)t0.w * t0.w
              + (double)t1.x * t1.x + (double)t1.y * t1.y + (double)t1.z * t1.z + (double)t1.w * t1.w
              + (double)t2.x * t2.x + (double)t2.y * t2.y + (double)t2.z * t2.z + (double)t2.w * t2.w
              + (double)t3.x * t3.x + (double)t3.y * t3.y + (double)t3.z * t3.z + (double)t3.w * t3.w;
#pragma unroll
    for (int off = 32; off; off >>= 1) {
      dd += __shfl_down(dd, off, 64);
      tt += __shfl_down(tt, off, 64);
    }
    if (lane == 0) cval[cc] = dd / (sn * fmax(sqrt(tt), 1e-8));
  }
  __syncthreads();

  if (tid == 0) {
    bool used[REFINE];
#pragma unroll
    for (int j = 0; j < REFINE; ++j) used[j] = false;
    for (int k = 0; k < KNN; ++k) {
      int bj = -1; double bv = 0.0; int bidx = 0x7fffffff;
      for (int j = 0; j < REFINE; ++j) {
        if (used[j]) continue;
        if (bj < 0 || cval[j] > bv || (cval[j] == bv && cand[j] < bidx)) {
          bj = j; bv = cval[j]; bidx = cand[j];
        }
      }
      used[bj] = true;
      fin[k] = cand[bj];
    }
  }
  __syncthreads();

  const int d = tid * 4;
  float4 a = *(const float4*)(tgt + ((size_t)fin[0] << 10) + d);
  float4 b = *(const float4*)(tgt + ((size_t)fin[1] << 10) + d);
  float4 c = *(const float4*)(tgt + ((size_t)fin[2] << 10) + d);
  float4 e = *(const float4*)(tgt + ((size_t)fin[3] << 10) + d);
  float4 o;
  o.x = 0.25f * (a.x + b.x + c.x + e.x);
  o.y = 0.25f * (a.y + b.y + c.y + e.y);
  o.z = 0.25f * (a.z + b.z + c.z + e.z);
  o.w = 0.25f * (a.w + b.w + c.w + e.w);
  *(float4*)(out + ((size_t)row << 10) + d) = o;
}

extern "C" void kernel_launch(void* const* d_in, const int* in_sizes, int n_in,
                              void* d_out, int out_size, void* d_ws, size_t ws_size,
                              hipStream_t stream) {
  const float* src = (const float*)d_in[0];
  const float* tgt = (const float*)d_in[1];
  float* out = (float*)d_out;
  char* ws = (char*)d_ws;

  const size_t SRCQ_B = (size_t)S_ROWS << 10;  // 2.10 MB (i8)
  const size_t TGTQ_B = (size_t)T_PAD << 10;   // 51.38 MB (i8)

  i8* srcq = (i8*)ws;
  i8* tgtq = (i8*)(ws + SRCQ_B);
  u64* partials = (u64*)(ws + SRCQ_B + TGTQ_B);  // 6.42 MB; total < 60 MB (ws >= 313 MB proven)

  quant_kernel<<<S_ROWS, 256, 0, stream>>>(src, srcq, S_ROWS);
  quant_kernel<<<T_PAD, 256, 0, stream>>>(tgt, tgtq, T_ROWS);

  dim3 g3(S_ROWS / BM, NUM_CHUNKS);  // x fastest => row-tiles share a tgt chunk in L2
  sim_i8_kernel<<<g3, 256, 0, stream>>>(srcq, tgtq, partials);

  merge_gather_kernel<<<S_ROWS, 256, 0, stream>>>(partials, src, tgt, out);
}